// Round 6
// baseline (53.400 us; speedup 1.0000x reference)
//
#include <hip/hip_runtime.h>
#include <cstddef>

typedef __attribute__((ext_vector_type(8))) short short8v;
typedef __attribute__((ext_vector_type(4))) short short4v;
typedef __attribute__((ext_vector_type(4))) float f32x4;

__device__ __forceinline__ unsigned short f2bf(float f) {
    unsigned u = __float_as_uint(f);
    u = (u + 0x7FFFu + ((u >> 16) & 1u)) >> 16;
    return (unsigned short)u;
}

// ---- prep (verified in R4): W[o][d][e][w] fp32 -> Wb frag-stream bf16 ----
// Wb[(g*64+f)*36864 + ks*2048 + nt*512 + lane*8 + j]
//   = bf16( W[o = g*64+nt*16+(lane&15), d = (lane>>4)*8+j, e = 2f+ks/9, w = ks%9] )
__global__ __launch_bounds__(256) void prep_w(const float* __restrict__ w,
                                              unsigned short* __restrict__ wb)
{
    const int g  = blockIdx.x >> 6;
    const int f  = blockIdx.x & 63;
    const int e0 = 2 * f;
    const int tid = threadIdx.x;
    __shared__ unsigned short ls[64 * 580];   // pitch 580 breaks power-of-2 banks

    #pragma unroll 4
    for (int i = 0; i < 72; ++i) {
        int fl  = tid + i * 256;           // (o_l,d) x 9 float2
        int od  = fl / 9;
        int f2i = fl - od * 9;
        int o_l = od >> 5;
        int d   = od & 31;
        const float2 v = *reinterpret_cast<const float2*>(
            &w[(size_t)((g * 64 + o_l) * 32 + d) * 1152 + e0 * 9 + f2i * 2]);
        ushort2 hh; hh.x = f2bf(v.x); hh.y = f2bf(v.y);
        *reinterpret_cast<ushort2*>(&ls[o_l * 580 + d * 18 + f2i * 2]) = hh;
    }
    __syncthreads();

    unsigned short* wo = wb + (size_t)(g * 64 + f) * 36864;
    #pragma unroll 2
    for (int i = 0; i < 18; ++i) {
        int oc   = tid + i * 256;          // (ks, nt, lane)
        int ks   = oc >> 8;
        int nt   = (oc >> 6) & 3;
        int lane = oc & 63;
        int li = lane & 15, hi = lane >> 4;
        int ec = (ks >= 9) ? 1 : 0;
        int w9 = ks - 9 * ec;
        int o_l = nt * 16 + li;
        short8v vv;
        #pragma unroll
        for (int j = 0; j < 8; ++j)
            vv[j] = (short)ls[o_l * 580 + (hi * 8 + j) * 18 + ec * 9 + w9];
        *reinterpret_cast<short8v*>(&wo[(size_t)oc * 8]) = vv;
    }
}

// ---- main: block = (g,f,h): 4 batches, 2 tiles x 2 e-phases, pipelined ----
// 4 waves, wave tile 64n x 64t (acc 4x4). A in LDS frag-stream (lane-linear,
// conflict-free); next phase's globals prefetched into regs during compute.
__global__ __launch_bounds__(256, 2) void lconv_mfma(const float* __restrict__ x,
                                                     const unsigned short* __restrict__ wb,
                                                     float* __restrict__ out)
{
    int bid = blockIdx.x;                       // 0..511
    int lid = (bid & 7) * 64 + (bid >> 3);      // XCD-chunked: h-pairs adjacent
    const int h = lid & 1;
    const int f = (lid >> 1) & 63;
    const int g = lid >> 7;
    const int e0 = 2 * f;

    const int tid  = threadIdx.x;
    const int lane = tid & 63;
    const int wv   = tid >> 6;
    const int bl   = wv & 1;        // batch within staged pair
    const int th   = wv >> 1;       // t-half
    const int li   = lane & 15;
    const int hi   = lane >> 4;
    const int t    = tid & 127;     // staging lane -> t
    const int z    = tid >> 7;      // staging batch-within-pair

    __shared__ __align__(16) unsigned short xs[2 * 136 * 40];   // 21760 B
    __shared__ __align__(16) unsigned short As[18432];          // 36864 B (58.6 KB tot)

    // zero pads once: tp in {0..3, 132..135}, both slots, all d
    if (tid < 128) {
        int blz = tid >> 6;
        int r   = (tid >> 3) & 7;
        int dq  = tid & 7;
        int tp  = (r < 4) ? r : (128 + r);
        short4v zz = {0, 0, 0, 0};
        *reinterpret_cast<short4v*>(&xs[(blz * 136 + tp) * 40 + dq * 4]) = zz;
    }

    const unsigned short* wslab = wb + (size_t)(g * 64 + f) * 36864;

    float   xr[32];
    short8v ar[9];

    f32x4 acc[4][4];
    #pragma unroll
    for (int nt = 0; nt < 4; ++nt)
        #pragma unroll
        for (int tt = 0; tt < 4; ++tt)
            acc[nt][tt] = (f32x4){0.f, 0.f, 0.f, 0.f};

    auto issue = [&](int p) {
        const int e  = e0 + (p & 1);
        const int b0 = h * 4 + (p >> 1) * 2 + z;
        const float* xp0 = &x[((size_t)(b0 * 128 + g * 32) * 128 + e) * 128 + t];
        #pragma unroll
        for (int i = 0; i < 8; ++i) {           // d = 4i + {0..3}
            const float* xp = xp0 + (size_t)i * 4 * 16384;
            xr[i * 4 + 0] = xp[0];
            xr[i * 4 + 1] = xp[16384];
            xr[i * 4 + 2] = xp[32768];
            xr[i * 4 + 3] = xp[49152];
        }
        const short8v* src = reinterpret_cast<const short8v*>(wslab + (size_t)(p & 1) * 18432);
        #pragma unroll
        for (int i = 0; i < 9; ++i) ar[i] = src[tid + i * 256];
    };

    auto lwrite = [&]() {
        #pragma unroll
        for (int i = 0; i < 8; ++i) {
            short4v hq;
            hq[0] = (short)f2bf(xr[i * 4 + 0]);
            hq[1] = (short)f2bf(xr[i * 4 + 1]);
            hq[2] = (short)f2bf(xr[i * 4 + 2]);
            hq[3] = (short)f2bf(xr[i * 4 + 3]);
            *reinterpret_cast<short4v*>(&xs[(z * 136 + t + 4) * 40 + i * 4]) = hq;
        }
        short8v* dst = reinterpret_cast<short8v*>(As);
        #pragma unroll
        for (int i = 0; i < 9; ++i) dst[tid + i * 256] = ar[i];
    };

    auto compute = [&]() {
        #pragma unroll
        for (int w9 = 0; w9 < 9; ++w9) {
            short8v Af[4], Bf[4];
            #pragma unroll
            for (int nt = 0; nt < 4; ++nt)      // lane-linear: conflict-free
                Af[nt] = *reinterpret_cast<const short8v*>(
                    &As[(w9 * 4 + nt) * 512 + lane * 8]);
            #pragma unroll
            for (int tt = 0; tt < 4; ++tt) {
                int tp = th * 64 + tt * 16 + li + w9;
                Bf[tt] = *reinterpret_cast<const short8v*>(
                    &xs[(bl * 136 + tp) * 40 + hi * 8]);
            }
            #pragma unroll
            for (int nt = 0; nt < 4; ++nt)
                #pragma unroll
                for (int tt = 0; tt < 4; ++tt)
                    acc[nt][tt] = __builtin_amdgcn_mfma_f32_16x16x32_bf16(
                        Af[nt], Bf[tt], acc[nt][tt], 0, 0, 0);
        }
    };

    auto store_tile = [&](int tl) {
        const int b = h * 4 + tl * 2 + bl;
        #pragma unroll
        for (int nt = 0; nt < 4; ++nt)
            #pragma unroll
            for (int tt = 0; tt < 4; ++tt)
                #pragma unroll
                for (int j = 0; j < 4; ++j) {
                    float v = acc[nt][tt][j];
                    v = (v >= 0.f) ? v : 0.01f * v;
                    int n  = nt * 16 + hi * 4 + j;
                    int tc = th * 64 + tt * 16 + li;
                    out[(((size_t)(b * 256 + g * 64 + n)) * 64 + f) * 128 + tc] = v;
                }
    };

    // ---- pipeline: p = (tile<<1)|ec ; issue(p+1) overlaps compute(p) ----
    issue(0);
    lwrite();                       // compiler waits vmcnt for xr/ar deps
    __syncthreads();

    issue(1);
    compute();                      // p0
    __syncthreads();
    lwrite();
    __syncthreads();

    issue(2);
    compute();                      // p1 -> tile0 complete
    store_tile(0);
    #pragma unroll
    for (int nt = 0; nt < 4; ++nt)
        #pragma unroll
        for (int tt = 0; tt < 4; ++tt)
            acc[nt][tt] = (f32x4){0.f, 0.f, 0.f, 0.f};
    __syncthreads();
    lwrite();
    __syncthreads();

    issue(3);
    compute();                      // p2
    __syncthreads();
    lwrite();
    __syncthreads();

    compute();                      // p3 -> tile1 complete
    store_tile(1);
}

extern "C" void kernel_launch(void* const* d_in, const int* in_sizes, int n_in,
                              void* d_out, int out_size, void* d_ws, size_t ws_size,
                              hipStream_t stream)
{
    const float* x = (const float*)d_in[0];           // (8,128,128,128) fp32
    const float* w = (const float*)d_in[1];           // (256,32,128,9) fp32
    float* out = (float*)d_out;                       // (8,256,64,128) fp32
    unsigned short* wb = (unsigned short*)d_ws;       // 4*64*36864 bf16 = 18.9 MB

    hipLaunchKernelGGL(prep_w, dim3(256), dim3(256), 0, stream, w, wb);
    hipLaunchKernelGGL(lconv_mfma, dim3(512), dim3(256), 0, stream, x, wb, out);
}